// Round 1
// baseline (67.050 us; speedup 1.0000x reference)
//
#include <hip/hip_runtime.h>
#include <math.h>

// Problem constants (fixed by the reference setup)
constexpr int Bb = 32;
constexpr int Ss = 2048;
constexpr int Hh = 1024;
constexpr int SC = 32;                 // s-rows per block in fused kernel
constexpr int CPB = Ss / SC;           // 64 chunks per batch
constexpr int NBLK = Bb * CPB;         // 2048 blocks

// ---------------- Kernel A: h = hidden @ W_in^T ----------------
// One wave per output element (b,i): dot(hidden[b,:], W_in[i,:]) over H=1024.
__global__ __launch_bounds__(256) void gemv_h_kernel(const float* __restrict__ hidden,
                                                     const float* __restrict__ W,
                                                     float* __restrict__ h)
{
    int tid  = threadIdx.x;
    int wid  = blockIdx.x * 4 + (tid >> 6);   // global wave id = b*H + i
    int lane = tid & 63;
    int b = wid >> 10;          // / H
    int i = wid & (Hh - 1);     // % H
    const float4* wr = reinterpret_cast<const float4*>(W + (size_t)i * Hh);
    const float4* hd = reinterpret_cast<const float4*>(hidden + (size_t)b * Hh);
    float d = 0.f;
#pragma unroll
    for (int k = 0; k < 4; ++k) {
        float4 wv = wr[lane + 64 * k];
        float4 hv = hd[lane + 64 * k];
        d += wv.x * hv.x + wv.y * hv.y + wv.z * hv.z + wv.w * hv.w;
    }
#pragma unroll
    for (int off = 32; off > 0; off >>= 1) d += __shfl_xor(d, off, 64);
    if (lane == 0) h[wid] = d;
}

// ---------------- Kernel B: fused scores + online softmax + partial context ----
// Block = (batch b, chunk of SC=32 rows). 4 waves, 8 rows per wave.
// Lane owns H-elements i = 4*lane + 256*k (k=0..3) as float4s.
__global__ __launch_bounds__(256) void attn_partial_kernel(const float* __restrict__ enc,
                                                           const float* __restrict__ h,
                                                           float* __restrict__ scores,
                                                           float* __restrict__ pm,
                                                           float* __restrict__ pl,
                                                           float* __restrict__ pctx)
{
    int blk   = blockIdx.x;           // 0..NBLK-1
    int b     = blk / CPB;
    int chunk = blk % CPB;
    int s0    = chunk * SC;
    int tid   = threadIdx.x;
    int wave  = tid >> 6;
    int lane  = tid & 63;

    // h fragment for this lane (i = 4*lane + 256*k)
    float4 hf[4];
    const float4* h4 = reinterpret_cast<const float4*>(h + (size_t)b * Hh);
#pragma unroll
    for (int k = 0; k < 4; ++k) hf[k] = h4[lane + 64 * k];

    float m = -INFINITY;
    float l = 0.f;
    float4 ctx[4];
#pragma unroll
    for (int k = 0; k < 4; ++k) ctx[k] = make_float4(0.f, 0.f, 0.f, 0.f);

    // 8 rows per wave
    for (int r = 0; r < 8; ++r) {
        int s = s0 + wave * 8 + r;
        const float4* e4 = reinterpret_cast<const float4*>(enc + ((size_t)b * Ss + s) * Hh);
        float4 ev[4];
#pragma unroll
        for (int k = 0; k < 4; ++k) ev[k] = e4[lane + 64 * k];
        float d = 0.f;
#pragma unroll
        for (int k = 0; k < 4; ++k)
            d += ev[k].x * hf[k].x + ev[k].y * hf[k].y + ev[k].z * hf[k].z + ev[k].w * hf[k].w;
#pragma unroll
        for (int off = 32; off > 0; off >>= 1) d += __shfl_xor(d, off, 64);
        // all lanes now hold the full score
        if (lane == 0) scores[(size_t)b * Ss + s] = d;

        if (d > m) {
            float c = __expf(m - d);   // exp(-inf)=0 on first row
            l *= c;
#pragma unroll
            for (int k = 0; k < 4; ++k) {
                ctx[k].x *= c; ctx[k].y *= c; ctx[k].z *= c; ctx[k].w *= c;
            }
            m = d;
        }
        float p = __expf(d - m);
        l += p;
#pragma unroll
        for (int k = 0; k < 4; ++k) {
            ctx[k].x += p * ev[k].x; ctx[k].y += p * ev[k].y;
            ctx[k].z += p * ev[k].z; ctx[k].w += p * ev[k].w;
        }
    }

    // intra-block combine across 4 waves via LDS
    __shared__ float lds_ctx[4][Hh];   // 16 KiB
    __shared__ float lds_m[4], lds_l[4];
    float4* ldsrow = reinterpret_cast<float4*>(lds_ctx[wave]);
#pragma unroll
    for (int k = 0; k < 4; ++k) ldsrow[64 * k + lane] = ctx[k];
    if (lane == 0) { lds_m[wave] = m; lds_l[wave] = l; }
    __syncthreads();

    float M = fmaxf(fmaxf(lds_m[0], lds_m[1]), fmaxf(lds_m[2], lds_m[3]));
    float L = 0.f;
    float4 acc = make_float4(0.f, 0.f, 0.f, 0.f);
#pragma unroll
    for (int w = 0; w < 4; ++w) {
        float c = __expf(lds_m[w] - M);
        L += c * lds_l[w];
        float4 v = reinterpret_cast<float4*>(lds_ctx[w])[tid];
        acc.x += c * v.x; acc.y += c * v.y; acc.z += c * v.z; acc.w += c * v.w;
    }
    reinterpret_cast<float4*>(pctx + (size_t)blk * Hh)[tid] = acc;
    if (tid == 0) { pm[blk] = M; pl[blk] = L; }
}

// ---------------- Kernel C: combine chunk partials per batch -> context -------
__global__ __launch_bounds__(256) void combine_kernel(const float* __restrict__ pm,
                                                      const float* __restrict__ pl,
                                                      const float* __restrict__ pctx,
                                                      float* __restrict__ out_ctx,
                                                      float* __restrict__ Mb,
                                                      float* __restrict__ Lb)
{
    int b   = blockIdx.x;
    int tid = threadIdx.x;
    const float* mrow = pm + (size_t)b * CPB;
    const float* lrow = pl + (size_t)b * CPB;

    float M = -INFINITY;
    for (int c = 0; c < CPB; ++c) M = fmaxf(M, mrow[c]);
    float L = 0.f;
    float4 acc = make_float4(0.f, 0.f, 0.f, 0.f);
    for (int c = 0; c < CPB; ++c) {
        float sc = __expf(mrow[c] - M);
        L += sc * lrow[c];
        float4 v = reinterpret_cast<const float4*>(pctx + ((size_t)b * CPB + c) * Hh)[tid];
        acc.x += sc * v.x; acc.y += sc * v.y; acc.z += sc * v.z; acc.w += sc * v.w;
    }
    float inv = 1.f / L;
    float4 o = make_float4(acc.x * inv, acc.y * inv, acc.z * inv, acc.w * inv);
    reinterpret_cast<float4*>(out_ctx + (size_t)b * Hh)[tid] = o;
    if (tid == 0) { Mb[b] = M; Lb[b] = L; }
}

// ---------------- Kernel D: normalize scores -> attn_w ------------------------
__global__ __launch_bounds__(256) void finish_attn_kernel(const float* __restrict__ scores,
                                                          const float* __restrict__ Mb,
                                                          const float* __restrict__ Lb,
                                                          float* __restrict__ attn_out)
{
    int idx = blockIdx.x * 256 + threadIdx.x;   // 0..B*S-1
    int b = idx >> 11;                          // / S
    float inv = 1.f / Lb[b];
    attn_out[idx] = __expf(scores[idx] - Mb[b]) * inv;
}

extern "C" void kernel_launch(void* const* d_in, const int* in_sizes, int n_in,
                              void* d_out, int out_size, void* d_ws, size_t ws_size,
                              hipStream_t stream) {
    const float* hidden = (const float*)d_in[0];   // [B,H]
    const float* enc    = (const float*)d_in[1];   // [B,S,H]
    const float* W_in   = (const float*)d_in[2];   // [H,H]

    float* out_ctx  = (float*)d_out;               // [B,H]   context first
    float* out_attn = (float*)d_out + Bb * Hh;     // [B,S]

    float* ws     = (float*)d_ws;
    float* h      = ws;                            // B*H      = 32768
    float* scores = ws + 32768;                    // B*S      = 65536
    float* pm     = ws + 98304;                    // NBLK     = 2048
    float* pl     = ws + 100352;                   // NBLK     = 2048
    float* pctx   = ws + 102400;                   // NBLK*H   = 2097152
    float* Mb     = ws + 102400 + (size_t)NBLK * Hh;  // 32
    float* Lb     = Mb + Bb;                       // 32
    (void)in_sizes; (void)n_in; (void)out_size; (void)ws_size;

    // A: h = hidden @ W_in^T   (B*H waves, 4 waves/block)
    gemv_h_kernel<<<(Bb * Hh) / 4, 256, 0, stream>>>(hidden, W_in, h);
    // B: fused scores + online softmax + partial context (single enc pass)
    attn_partial_kernel<<<NBLK, 256, 0, stream>>>(enc, h, scores, pm, pl, pctx);
    // C: per-batch combine -> context + exact (M, L)
    combine_kernel<<<Bb, 256, 0, stream>>>(pm, pl, pctx, out_ctx, Mb, Lb);
    // D: attn_w = exp(score - M)/L
    finish_attn_kernel<<<(Bb * Ss) / 256, 256, 0, stream>>>(scores, Mb, Lb, out_attn);
}